// Round 3
// baseline (442.607 us; speedup 1.0000x reference)
//
#include <hip/hip_runtime.h>
#include <cstdint>

// GaussianAgg: z_map construction + S=16 perturbed argmaxes -> mean one-hot.
// HBM-bound: noise [16,131072,33] f32 = 277 MB read-once dominates (361 MB total
// -> ~57 us floor @ 6.3 TB/s achievable).
// R2 lesson: global_load_lds with divergent lds_ptr in a rolled/predicated loop
// corrupted LDS (late DMA clobbered the epilogue buffer). This version uses
// plain vector loads with REGISTER-RELAY double buffering: 9 float4 loads of
// tile(s+1) are all in flight while argmax(s) computes from LDS; the vmcnt
// drain happens naturally at the next ds_write.

#define NPIX    131072
#define KCH     32
#define CCH     33               // K + background
#define SAMP    16
#define TPB     128
#define TILE_F  (TPB * CCH)      // 4224 floats = 16.9 KB
#define TILE_V4 (TILE_F / 4)     // 1056 float4
#define FULL_J  (TILE_V4 / TPB)  // 8 full strided iterations
#define REM     (TILE_V4 % TPB)  // 32-thread tail

__global__ __launch_bounds__(TPB)
void gauss_agg_kernel(const float* __restrict__ zbuf,
                      const float* __restrict__ zfar_p,
                      const float* __restrict__ znear_p,
                      const float* __restrict__ prob,
                      const float* __restrict__ mask,
                      const float* __restrict__ noise,
                      float* __restrict__ out)
{
#pragma clang fp contract(off)
    __shared__ float buf[TILE_F];
    const int tid = threadIdx.x;
    const int p0  = blockIdx.x * TPB;
    const size_t p = (size_t)p0 + tid;

    const float zfar  = zfar_p[0];
    const float znear = znear_p[0];
    const float denom = zfar - znear;

    // ---- per-pixel rows: 32 contiguous floats @128B-aligned base. Direct
    // float4 loads: lane stride 128B = one cache line per pixel, fully reused
    // across the 8-way unroll -> fetch == footprint.
    float zb[KCH], pm[KCH], mk[KCH];
    {
        const float4* zb4 = reinterpret_cast<const float4*>(zbuf + p * KCH);
        const float4* pm4 = reinterpret_cast<const float4*>(prob + p * KCH);
        const float4* mk4 = reinterpret_cast<const float4*>(mask + p * KCH);
        #pragma unroll
        for (int i = 0; i < KCH / 4; ++i) {
            float4 a = zb4[i], b = pm4[i], c = mk4[i];
            zb[4*i+0] = a.x; zb[4*i+1] = a.y; zb[4*i+2] = a.z; zb[4*i+3] = a.w;
            pm[4*i+0] = b.x; pm[4*i+1] = b.y; pm[4*i+2] = b.z; pm[4*i+3] = b.w;
            mk[4*i+0] = c.x; mk[4*i+1] = c.y; mk[4*i+2] = c.z; mk[4*i+3] = c.w;
        }
    }

    // ---- prologue: noise tile(0) -> registers (9 loads, all in flight)
    float4 r[FULL_J + 1];
    {
        const float4* g4 = reinterpret_cast<const float4*>(
            noise + (size_t)p0 * CCH);
        #pragma unroll
        for (int j = 0; j < FULL_J; ++j) r[j] = g4[tid + j * TPB];
        if (tid < REM) r[FULL_J] = g4[tid + FULL_J * TPB];
    }

    // ---- z_inv + zmax (rounding order identical to R1, which passed absmax 0)
    float z_inv[KCH];
    float zmax = 1e-10f;
    #pragma unroll
    for (int k = 0; k < KCH; ++k) {
        float zi = ((zfar - zb[k]) / denom) * mk[k];
        z_inv[k] = zi;
        zmax = fmaxf(zmax, zi);
    }

    // ---- z_map: ((g*log) + z_inv) - zmax
    float z_map[CCH];
    #pragma unroll
    for (int k = 0; k < KCH; ++k) {
        float lg = logf(1e-12f + pm[k]);
        z_map[k] = ((0.04f * lg) + z_inv[k]) - zmax;
    }
    z_map[KCH] = 1e-10f - zmax;

    int acc[CCH];
    #pragma unroll
    for (int c = 0; c < CCH; ++c) acc[c] = 0;

    // ---- sample loop: regs hold tile(s); write to LDS; prefetch tile(s+1)
    for (int s = 0; s < SAMP; ++s) {
        if (s) __syncthreads();              // everyone done reading tile(s-1)
        {
            float4* l4 = reinterpret_cast<float4*>(buf);
            #pragma unroll
            for (int j = 0; j < FULL_J; ++j) l4[tid + j * TPB] = r[j];
            if (tid < REM) l4[tid + FULL_J * TPB] = r[FULL_J];
        }
        __syncthreads();                     // tile(s) visible to all
        if (s + 1 < SAMP) {                  // prefetch overlaps compute below
            const float4* g4 = reinterpret_cast<const float4*>(
                noise + ((size_t)(s + 1) * NPIX + p0) * CCH);
            #pragma unroll
            for (int j = 0; j < FULL_J; ++j) r[j] = g4[tid + j * TPB];
            if (tid < REM) r[FULL_J] = g4[tid + FULL_J * TPB];
        }
        // first-max argmax (strict >) over z_map + 0.04*noise; own row in LDS,
        // 2-way bank alias only (free per m136)
        const float* nb = buf + tid * CCH;
        float best = z_map[0] + (0.04f * nb[0]);
        int bi = 0;
        #pragma unroll
        for (int c = 1; c < CCH; ++c) {
            float v = z_map[c] + (0.04f * nb[c]);
            if (v > best) { best = v; bi = c; }
        }
        #pragma unroll
        for (int c = 0; c < CCH; ++c) acc[c] += (bi == c);
    }

    // ---- epilogue: counts/16 via LDS (own row write after own row read - no
    // barrier needed before), then coalesced float4 stores
    {
        const int rb = tid * CCH;
        #pragma unroll
        for (int c = 0; c < CCH; ++c) buf[rb + c] = (float)acc[c] * 0.0625f;
    }
    __syncthreads();
    {
        const float4* l4 = reinterpret_cast<const float4*>(buf);
        float4* o4 = reinterpret_cast<float4*>(out + (size_t)p0 * CCH);
        #pragma unroll
        for (int j = 0; j < FULL_J; ++j) o4[tid + j * TPB] = l4[tid + j * TPB];
        if (tid < REM) o4[tid + FULL_J * TPB] = l4[tid + FULL_J * TPB];
    }
}

extern "C" void kernel_launch(void* const* d_in, const int* in_sizes, int n_in,
                              void* d_out, int out_size, void* d_ws, size_t ws_size,
                              hipStream_t stream)
{
    const float* zbuf  = (const float*)d_in[0];
    const float* zfar  = (const float*)d_in[1];
    const float* znear = (const float*)d_in[2];
    const float* prob  = (const float*)d_in[3];
    const float* mask  = (const float*)d_in[4];
    const float* noise = (const float*)d_in[5];
    float* out = (float*)d_out;

    dim3 grid(NPIX / TPB), block(TPB);
    gauss_agg_kernel<<<grid, block, 0, stream>>>(zbuf, zfar, znear, prob, mask,
                                                 noise, out);
}